// Round 24
// baseline (643.066 us; speedup 1.0000x reference)
//
#include <hip/hip_runtime.h>
#include <hip/hip_bf16.h>
#include <hip/hip_fp16.h>

#define Dh 2048
#define Bh 4
#define Sh 2048
#define NROW 8192          // B*S
#define HALF 1024
#define INV_SQRT_D 0.022097086912079608f
#define LNEPS 1e-5f

typedef __hip_bfloat16 bf16;
typedef short short8 __attribute__((ext_vector_type(8)));
typedef float f32x4 __attribute__((ext_vector_type(4)));
typedef unsigned short ushort8v __attribute__((ext_vector_type(8)));
typedef unsigned short ushort4v __attribute__((ext_vector_type(4)));

__device__ inline float h2f_bits(unsigned short u) {
  __half h;
  *(unsigned short*)&h = u;
  return __half2float(h);
}
__device__ inline unsigned short bf_bits(float f) {
  bf16 t = __float2bfloat16(f);
  return *(unsigned short*)&t;
}

__device__ inline float warp_sum(float x) {
#pragma unroll
  for (int o = 32; o > 0; o >>= 1) x += __shfl_down(x, o);
  return x;
}
__device__ inline float warp_max(float x) {
#pragma unroll
  for (int o = 32; o > 0; o >>= 1) x = fmaxf(x, __shfl_down(x, o));
  return x;
}
__device__ inline float block_sum(float x, float* sm4) {
  x = warp_sum(x);
  int w = threadIdx.x >> 6;
  if ((threadIdx.x & 63) == 0) sm4[w] = x;
  __syncthreads();
  float r = sm4[0] + sm4[1] + sm4[2] + sm4[3];
  __syncthreads();
  return r;
}
__device__ inline float block_max(float x, float* sm4) {
  x = warp_max(x);
  int w = threadIdx.x >> 6;
  if ((threadIdx.x & 63) == 0) sm4[w] = x;
  __syncthreads();
  float r = fmaxf(fmaxf(sm4[0], sm4[1]), fmaxf(sm4[2], sm4[3]));
  __syncthreads();
  return r;
}

// async global->LDS, 16B per lane; LDS dest is wave-uniform base + lane*16
__device__ inline void gload_lds16(const void* g, void* lds) {
  __builtin_amdgcn_global_load_lds(
      (const __attribute__((address_space(1))) unsigned int*)(unsigned long long)g,
      (__attribute__((address_space(3))) unsigned int*)(unsigned long long)lds,
      16, 0, 0);
}

#define MMQ(FR, FC, AV, BV)                                                    \
  acc[FR][FC] = __builtin_amdgcn_mfma_f32_16x16x32_bf16(AV, BV, acc[FR][FC], 0, 0, 0);

#define MM4(R, AF, B0, B1, B2, B3)                                             \
  acc[R][0] = __builtin_amdgcn_mfma_f32_16x16x32_bf16(AF, B0, acc[R][0], 0, 0, 0); \
  acc[R][1] = __builtin_amdgcn_mfma_f32_16x16x32_bf16(AF, B1, acc[R][1], 0, 0, 0); \
  acc[R][2] = __builtin_amdgcn_mfma_f32_16x16x32_bf16(AF, B2, acc[R][2], 0, 0, 0); \
  acc[R][3] = __builtin_amdgcn_mfma_f32_16x16x32_bf16(AF, B3, acc[R][3], 0, 0, 0);

// ---------------------------------------------------------------------------
// MFMA bf16 GEMM, R24: m201-style 4-phase QUADRANT cadence on the validated
// R18 memory schedule. C[M,N] = A[M,K] @ B[N,K]^T. 256x256 tile, BK=64,
// 16x16x32 MFMA, 8 waves (2Mx4N), per-wave 128x64. LDS 160KB: A 2x32KB
// (t&1) + B 3x32KB (t%3).
// Per tile, 4 phases, each {reads | 2-gload stage | barrier | lgkmcnt(0) |
// setprio(1) 16 MFMA setprio(0) | barrier}:
//  ph0 q(fr0-3,fc0-1): 12 reads (B fc0-1 both kk + A fr0-3 both kk) | A(t+1)h0
//  ph1 q(fr0-3,fc2-3):  4 reads (B fc2-3 both kk)                  | A(t+1)h1
//  ph2 q(fr4-7,fc2-3):  8 reads (A fr4-7 both kk)                  | B(t+2)h0
//  ph3 q(fr4-7,fc0-1):  0 reads (all retained)                     | B(t+2)h1
// B frags + current A-half retained in regs (64 VGPR inputs).
// Memory schedule (stage targets, region rotation, end-of-tile gate) is
// IDENTICAL to R18 (validated 5 rounds): vmcnt ledger: prologue
// A0+B0+B1=12, need 8 -> vmcnt(4); steady end-of-t: B(t+1)[4]+A(t+1)[4]
// +B(t+2)[4]=12, need 8 -> vmcnt(4); tail vmcnt(0). All this-tile ds_reads
// drain at their phase's lgkmcnt(0), before any same-region DMA next tile.
// MODE 1 z==2 (V): LDS-staged transposed epilogue (R21, validated).
// MODE 0: C bf16 = acc (prc)
// MODE 1: C bf16 = silu(acc + e0[z*D+c]) * e1[(z*4+b)*D+c]; z==2 -> vt
// MODE 2: C f16 = acc*INV_SQRT_D, skip blocks above causal diagonal (QK^T)
// MODE 4: C f32 = x + gating_o * silu(acc + mu_b3)  (o-proj + residual)
// ---------------------------------------------------------------------------
template <int MODE>
__global__ __launch_bounds__(512) void pgemm(
    const bf16* __restrict__ Aall, const bf16* __restrict__ Ball,
    void* __restrict__ Call, int N, int K, int lda, int ldb,
    long sAz, long sBz, long sCz,
    const float* __restrict__ e0, const float* __restrict__ e1,
    const float* __restrict__ e2, bf16* __restrict__ vt) {
  const int bm0 = blockIdx.x * 256;
  const int bn0 = blockIdx.y * 256;
  if (MODE == 2 && bn0 > bm0 + 255) return;  // fully above causal diagonal
  const int z = blockIdx.z;
  const bf16* A = Aall + (long)z * sAz;
  const bf16* B = Ball + (long)z * sBz;

  __shared__ __align__(16) char smem[163840];  // A 2x32K | B 3x32K @65536
  const int tid = threadIdx.x;
  const int l = tid & 63, w = tid >> 6;
  const int wr = w >> 2, wc = w & 3;  // wave grid 2x4

  f32x4 acc[8][4] = {};
  const int nt = K >> 6;

  const int sg = (((l & 7) ^ ((l >> 3) & 7)) << 3);  // pre-swizzled granule
  const int srow = (w << 3) + (l >> 3);
  const bf16* aS0 = A + (long)(bm0 + srow) * lda + sg;
  const bf16* aS1 = A + (long)(bm0 + 64 + srow) * lda + sg;
  const bf16* aS2 = A + (long)(bm0 + 128 + srow) * lda + sg;
  const bf16* aS3 = A + (long)(bm0 + 192 + srow) * lda + sg;
  const bf16* bT0 = B + (long)(bn0 + srow) * ldb + sg;
  const bf16* bT1 = B + (long)(bn0 + 64 + srow) * ldb + sg;
  const bf16* bT2 = B + (long)(bn0 + 128 + srow) * ldb + sg;
  const bf16* bT3 = B + (long)(bn0 + 192 + srow) * ldb + sg;
  char* const dA = smem + (w << 10);
  char* const dB = smem + 65536 + (w << 10);

  auto stageA = [&](int tt) {
    int boff = (tt & 1) << 15;
    gload_lds16(aS0 + (tt << 6), dA + boff);
    gload_lds16(aS1 + (tt << 6), dA + boff + 8192);
    gload_lds16(aS2 + (tt << 6), dA + boff + 16384);
    gload_lds16(aS3 + (tt << 6), dA + boff + 24576);
  };
  auto stageB = [&](int tt) {
    int boff = (tt % 3) << 15;
    gload_lds16(bT0 + (tt << 6), dB + boff);
    gload_lds16(bT1 + (tt << 6), dB + boff + 8192);
    gload_lds16(bT2 + (tt << 6), dB + boff + 16384);
    gload_lds16(bT3 + (tt << 6), dB + boff + 24576);
  };

  stageA(0); stageB(0);
  if (nt > 1) stageB(1);
  if (nt > 1) asm volatile("s_waitcnt vmcnt(4)" ::: "memory");
  else        asm volatile("s_waitcnt vmcnt(0)" ::: "memory");
  __builtin_amdgcn_sched_barrier(0);
  asm volatile("s_barrier" ::: "memory");

  const int rslot = (((l >> 4) ^ (l & 7)) << 4);
  const int abyte = (((wr << 7) + (l & 15)) << 7) + rslot;
  const int bbyte = (((wc << 6) + (l & 15)) << 7) + rslot;

  for (int t = 0; t < nt; ++t) {
    const char* Ab = smem + ((t & 1) << 15);
    const char* Bb = smem + 65536 + ((t % 3) << 15);
    short8 a0, a1, a2, a3, c0, c1, c2, c3;

    // ---- ph0: q(fr0-3, fc0-1). 12 reads | stage A(t+1) half0 ----
    short8 b00 = *(const short8*)(Bb + bbyte);
    short8 b01 = *(const short8*)(Bb + bbyte + 2048);
    short8 b10 = *(const short8*)(Bb + (bbyte ^ 64));
    short8 b11 = *(const short8*)(Bb + ((bbyte + 2048) ^ 64));
    a0 = *(const short8*)(Ab + abyte);
    a1 = *(const short8*)(Ab + abyte + 2048);
    a2 = *(const short8*)(Ab + abyte + 4096);
    a3 = *(const short8*)(Ab + abyte + 6144);
    c0 = *(const short8*)(Ab + (abyte ^ 64));
    c1 = *(const short8*)(Ab + ((abyte + 2048) ^ 64));
    c2 = *(const short8*)(Ab + ((abyte + 4096) ^ 64));
    c3 = *(const short8*)(Ab + ((abyte + 6144) ^ 64));
    if (t + 1 < nt) {
      int boff = ((t + 1) & 1) << 15;
      gload_lds16(aS0 + ((t + 1) << 6), dA + boff);
      gload_lds16(aS1 + ((t + 1) << 6), dA + boff + 8192);
    }
    asm volatile("s_barrier" ::: "memory");
    asm volatile("s_waitcnt lgkmcnt(0)" ::: "memory");
    __builtin_amdgcn_sched_barrier(0);
    __builtin_amdgcn_s_setprio(1);
    MMQ(0, 0, a0, b00) MMQ(1, 0, a1, b00) MMQ(2, 0, a2, b00) MMQ(3, 0, a3, b00)
    MMQ(0, 1, a0, b01) MMQ(1, 1, a1, b01) MMQ(2, 1, a2, b01) MMQ(3, 1, a3, b01)
    MMQ(0, 0, c0, b10) MMQ(1, 0, c1, b10) MMQ(2, 0, c2, b10) MMQ(3, 0, c3, b10)
    MMQ(0, 1, c0, b11) MMQ(1, 1, c1, b11) MMQ(2, 1, c2, b11) MMQ(3, 1, c3, b11)
    __builtin_amdgcn_s_setprio(0);
    asm volatile("s_barrier" ::: "memory");

    // ---- ph1: q(fr0-3, fc2-3). 4 reads | stage A(t+1) half1 ----
    short8 b02 = *(const short8*)(Bb + bbyte + 4096);
    short8 b03 = *(const short8*)(Bb + bbyte + 6144);
    short8 b12 = *(const short8*)(Bb + ((bbyte + 4096) ^ 64));
    short8 b13 = *(const short8*)(Bb + ((bbyte + 6144) ^ 64));
    if (t + 1 < nt) {
      int boff = ((t + 1) & 1) << 15;
      gload_lds16(aS2 + ((t + 1) << 6), dA + boff + 16384);
      gload_lds16(aS3 + ((t + 1) << 6), dA + boff + 24576);
    }
    asm volatile("s_barrier" ::: "memory");
    asm volatile("s_waitcnt lgkmcnt(0)" ::: "memory");
    __builtin_amdgcn_sched_barrier(0);
    __builtin_amdgcn_s_setprio(1);
    MMQ(0, 2, a0, b02) MMQ(1, 2, a1, b02) MMQ(2, 2, a2, b02) MMQ(3, 2, a3, b02)
    MMQ(0, 3, a0, b03) MMQ(1, 3, a1, b03) MMQ(2, 3, a2, b03) MMQ(3, 3, a3, b03)
    MMQ(0, 2, c0, b12) MMQ(1, 2, c1, b12) MMQ(2, 2, c2, b12) MMQ(3, 2, c3, b12)
    MMQ(0, 3, c0, b13) MMQ(1, 3, c1, b13) MMQ(2, 3, c2, b13) MMQ(3, 3, c3, b13)
    __builtin_amdgcn_s_setprio(0);
    asm volatile("s_barrier" ::: "memory");

    // ---- ph2: q(fr4-7, fc2-3). 8 reads | stage B(t+2) half0 ----
    a0 = *(const short8*)(Ab + abyte + 8192);
    a1 = *(const short8*)(Ab + abyte + 10240);
    a2 = *(const short8*)(Ab + abyte + 12288);
    a3 = *(const short8*)(Ab + abyte + 14336);
    c0 = *(const short8*)(Ab + ((abyte + 8192) ^ 64));
    c1 = *(const short8*)(Ab + ((abyte + 10240) ^ 64));
    c2 = *(const short8*)(Ab + ((abyte + 12288) ^ 64));
    c3 = *(const short8*)(Ab + ((abyte + 14336) ^ 64));
    if (t + 2 < nt) {
      int boff = ((t + 2) % 3) << 15;
      gload_lds16(bT0 + ((t + 2) << 6), dB + boff);
      gload_lds16(bT1 + ((t + 2) << 6), dB + boff + 8192);
    }
    asm volatile("s_barrier" ::: "memory");
    asm volatile("s_waitcnt lgkmcnt(0)" ::: "memory");
    __builtin_amdgcn_sched_barrier(0);
    __builtin_amdgcn_s_setprio(1);
    MMQ(4, 2, a0, b02) MMQ(5, 2, a1, b02) MMQ(6, 2, a2, b02) MMQ(7, 2, a3, b02)
    MMQ(4, 3, a0, b03) MMQ(5, 3, a1, b03) MMQ(6, 3, a2, b03) MMQ(7, 3, a3, b03)
    MMQ(4, 2, c0, b12) MMQ(5, 2, c1, b12) MMQ(6, 2, c2, b12) MMQ(7, 2, c3, b12)
    MMQ(4, 3, c0, b13) MMQ(5, 3, c1, b13) MMQ(6, 3, c2, b13) MMQ(7, 3, c3, b13)
    __builtin_amdgcn_s_setprio(0);
    asm volatile("s_barrier" ::: "memory");

    // ---- ph3: q(fr4-7, fc0-1). 0 reads | stage B(t+2) half1 ----
    if (t + 2 < nt) {
      int boff = ((t + 2) % 3) << 15;
      gload_lds16(bT2 + ((t + 2) << 6), dB + boff + 16384);
      gload_lds16(bT3 + ((t + 2) << 6), dB + boff + 24576);
    }
    asm volatile("s_barrier" ::: "memory");
    __builtin_amdgcn_s_setprio(1);
    MMQ(4, 0, a0, b00) MMQ(5, 0, a1, b00) MMQ(6, 0, a2, b00) MMQ(7, 0, a3, b00)
    MMQ(4, 1, a0, b01) MMQ(5, 1, a1, b01) MMQ(6, 1, a2, b01) MMQ(7, 1, a3, b01)
    MMQ(4, 0, c0, b10) MMQ(5, 0, c1, b10) MMQ(6, 0, c2, b10) MMQ(7, 0, c3, b10)
    MMQ(4, 1, c0, b11) MMQ(5, 1, c1, b11) MMQ(6, 1, c2, b11) MMQ(7, 1, c3, b11)
    __builtin_amdgcn_s_setprio(0);
    // end-of-tile gate (R18 ledger)
    if (t < nt - 1) {
      if (t + 2 < nt) asm volatile("s_waitcnt vmcnt(4)" ::: "memory");
      else            asm volatile("s_waitcnt vmcnt(0)" ::: "memory");
      __builtin_amdgcn_sched_barrier(0);
      asm volatile("s_barrier" ::: "memory");
    }
  }

  // epilogue: C/D mapping col = lane&15, row = (lane>>4)*4 + reg
  const int lc = l & 15, lr4 = (l >> 4) << 2;
  if (MODE == 1 && z == 2) {
    // V: LDS-staged transpose. Padded [col][264] ushort tile (135KB).
    unsigned short* tl = (unsigned short*)smem;
    const int bb = bm0 >> 11, s0r = bm0 & 2047;
    __syncthreads();  // all waves done reading staged A/B
#pragma unroll
    for (int fr = 0; fr < 8; ++fr) {
      int row0 = (wr << 7) + fr * 16 + lr4;
#pragma unroll
      for (int fc = 0; fc < 4; ++fc) {
        int col = (wc << 6) + fc * 16 + lc;
        int gc = bn0 + col;
        ushort4v u;
#pragma unroll
        for (int qv = 0; qv < 4; ++qv) {
          float val = acc[fr][fc][qv] + e0[2 * Dh + gc];
          float sil = val / (1.f + __expf(-val));
          u[qv] = bf_bits(sil * e1[(2 * Bh + bb) * Dh + gc]);
        }
        *(ushort4v*)(tl + col * 264 + row0) = u;
      }
    }
    __syncthreads();
#pragma unroll
    for (int it = 0; it < 4; ++it) {
      int idx = tid + it * 512;
      int col = idx >> 3, ch = idx & 7;
      const ushort8v* src = (const ushort8v*)(tl + col * 264 + ch * 32);
      ushort8v v0 = src[0], v1 = src[1], v2 = src[2], v3 = src[3];
      ushort8v* dst = (ushort8v*)((unsigned short*)vt +
          ((long)bb * Dh + bn0 + col) * Sh + s0r + ch * 32);
      dst[0] = v0; dst[1] = v1; dst[2] = v2; dst[3] = v3;
    }
  } else {
#pragma unroll
    for (int fr = 0; fr < 8; ++fr) {
      int gr0 = bm0 + (wr << 7) + fr * 16 + lr4;
#pragma unroll
      for (int fc = 0; fc < 4; ++fc) {
        int gc = bn0 + (wc << 6) + fc * 16 + lc;
#pragma unroll
        for (int qv = 0; qv < 4; ++qv) {
          int gr = gr0 + qv;
          float a = acc[fr][fc][qv];
          if (MODE == 0) {
            ((bf16*)Call + (long)z * sCz)[(long)gr * N + gc] =
                __float2bfloat16(a);
          } else if (MODE == 1) {
            float val = a + e0[z * Dh + gc];
            float sil = val / (1.f + __expf(-val));
            int bb = gr >> 11;
            float g = e1[(z * Bh + bb) * Dh + gc];
            ((bf16*)Call + (long)z * sCz)[(long)gr * N + gc] =
                __float2bfloat16(sil * g);
          } else if (MODE == 2) {
            ((__half*)Call + (long)z * sCz)[(long)gr * N + gc] =
                __float2half(a * INV_SQRT_D);
          } else {
            float val = a + e0[gc];
            float sil = val / (1.f + __expf(-val));
            int bb = gr >> 11;
            ((float*)Call)[(long)gr * N + gc] =
                e2[(long)gr * N + gc] + e1[bb * Dh + gc] * sil;
          }
        }
      }
    }
  }
}

// ---------------------------------------------------------------------------
// Balanced causal PV GEMM (R19 structure, validated): attn = probs @ vT^T.
// BK=64, BM=128, BN=256, 8 waves 2x4, per-wave 64x64. LDS 128KB.
// One barrier per tile. 512 blocks, complementary remap.
// ---------------------------------------------------------------------------
__global__ __launch_bounds__(512) void pgemm_h(
    const bf16* __restrict__ Aall, const bf16* __restrict__ Ball,
    bf16* __restrict__ Call, int N, int lda, int ldb,
    long sAz, long sBz, long sCz) {
  const int fid = blockIdx.x;
  const int p = fid >> 8, q = fid & 255;
  const int mh = q >> 5;
  const int z = (q >> 3) & 3, ni = q & 7;
  const int mi = p ? (15 - mh) : mh;
  const int bm0 = mi * 128, bn0 = ni * 256;
  const bf16* A = Aall + (long)z * sAz;
  const bf16* B = Ball + (long)z * sBz;

  __shared__ __align__(16) char smem[131072];  // A 2x16K | B 3x32K @32768
  const int tid = threadIdx.x;
  const int l = tid & 63, w = tid >> 6;
  const int wr = w >> 2, wc = w & 3;
  f32x4 acc[4][4] = {};
  const int nt = (bm0 + 128) >> 6;  // 2..32

  const int sg = (((l & 7) ^ ((l >> 3) & 7)) << 3);
  const int srow = (w << 3) + (l >> 3);
  const bf16* aS0 = A + (long)(bm0 + srow) * lda + sg;
  const bf16* aS1 = A + (long)(bm0 + 64 + srow) * lda + sg;
  const bf16* bT0 = B + (long)(bn0 + srow) * ldb + sg;
  const bf16* bT1 = B + (long)(bn0 + 64 + srow) * ldb + sg;
  const bf16* bT2 = B + (long)(bn0 + 128 + srow) * ldb + sg;
  const bf16* bT3 = B + (long)(bn0 + 192 + srow) * ldb + sg;
  char* const dA = smem + (w << 10);
  char* const dB = smem + 32768 + (w << 10);

  auto stageA = [&](int tt) {
    int boff = (tt & 1) << 14;
    gload_lds16(aS0 + (tt << 6), dA + boff);
    gload_lds16(aS1 + (tt << 6), dA + boff + 8192);
  };
  auto stageB = [&](int tt) {
    int boff = (tt % 3) << 15;
    gload_lds16(bT0 + (tt << 6), dB + boff);
    gload_lds16(bT1 + (tt << 6), dB + boff + 8192);
    gload_lds16(bT2 + (tt << 6), dB + boff + 16384);
    gload_lds16(bT3 + (tt << 6), dB + boff + 24576);
  };

  stageA(0); stageB(0); stageB(1);   // nt >= 2 always
  asm volatile("s_waitcnt vmcnt(4)" ::: "memory");
  __builtin_amdgcn_sched_barrier(0);
  asm volatile("s_barrier" ::: "memory");

  const int rslot = (((l >> 4) ^ (l & 7)) << 4);
  const int abyte = (((wr << 6) + (l & 15)) << 7) + rslot;
  const int bbyte = (((wc << 6) + (l & 15)) << 7) + rslot;

  for (int t = 0; t < nt; ++t) {
    const char* Ab = smem + ((t & 1) << 14);
    const char* Bb = smem + 32768 + ((t % 3) << 15);
    short8 b00 = *(const short8*)(Bb + bbyte);
    short8 b01 = *(const short8*)(Bb + bbyte + 2048);
    short8 b02 = *(const short8*)(Bb + bbyte + 4096);
    short8 b03 = *(const short8*)(Bb + bbyte + 6144);
    short8 b10 = *(const short8*)(Bb + (bbyte ^ 64));
    short8 b11 = *(const short8*)(Bb + ((bbyte + 2048) ^ 64));
    short8 b12 = *(const short8*)(Bb + ((bbyte + 4096) ^ 64));
    short8 b13 = *(const short8*)(Bb + ((bbyte + 6144) ^ 64));
    short8 a0 = *(const short8*)(Ab + abyte);
    short8 a1 = *(const short8*)(Ab + abyte + 2048);
    short8 a2 = *(const short8*)(Ab + abyte + 4096);
    short8 a3 = *(const short8*)(Ab + abyte + 6144);
    if (t + 1 < nt) stageA(t + 1);
    MM4(0, a0, b00, b01, b02, b03) MM4(1, a1, b00, b01, b02, b03)
    MM4(2, a2, b00, b01, b02, b03) MM4(3, a3, b00, b01, b02, b03)
    short8 c0 = *(const short8*)(Ab + (abyte ^ 64));
    short8 c1 = *(const short8*)(Ab + ((abyte + 2048) ^ 64));
    short8 c2 = *(const short8*)(Ab + ((abyte + 4096) ^ 64));
    short8 c3 = *(const short8*)(Ab + ((abyte + 6144) ^ 64));
    if (t + 2 < nt) stageB(t + 2);
    MM4(0, c0, b10, b11, b12, b13) MM4(1, c1, b10, b11, b12, b13)
    MM4(2, c2, b10, b11, b12, b13) MM4(3, c3, b10, b11, b12, b13)
    if (t < nt - 1) {
      asm volatile("s_waitcnt lgkmcnt(0)" ::: "memory");
      if (t + 2 < nt) asm volatile("s_waitcnt vmcnt(4)" ::: "memory");
      else            asm volatile("s_waitcnt vmcnt(0)" ::: "memory");
      __builtin_amdgcn_sched_barrier(0);
      asm volatile("s_barrier" ::: "memory");
    }
  }

  const int lc = l & 15, lr4 = (l >> 4) << 2;
  bf16* C = Call + (long)z * sCz;
#pragma unroll
  for (int fr = 0; fr < 4; ++fr) {
    int gr0 = bm0 + (wr << 6) + fr * 16 + lr4;
#pragma unroll
    for (int fc = 0; fc < 4; ++fc) {
      int gc = bn0 + (wc << 6) + fc * 16 + lc;
#pragma unroll
      for (int qv = 0; qv < 4; ++qv)
        C[(long)(gr0 + qv) * N + gc] = __float2bfloat16(acc[fr][fc][qv]);
    }
  }
}

// f32 -> bf16 elementwise for 3 tensors of DD4 elements each (y selects)
__global__ __launch_bounds__(256) void cvt3_kernel(
    const float* __restrict__ s0, const float* __restrict__ s1,
    const float* __restrict__ s2, bf16* __restrict__ o0, bf16* __restrict__ o1,
    bf16* __restrict__ o2, long n) {
  const float* in = (blockIdx.y == 0) ? s0 : (blockIdx.y == 1) ? s1 : s2;
  bf16* out = (blockIdx.y == 0) ? o0 : (blockIdx.y == 1) ? o1 : o2;
  long i = ((long)blockIdx.x * 256 + threadIdx.x) * 4;
  if (i >= n) return;
  float4 v = *(const float4*)(in + i);
  out[i + 0] = __float2bfloat16(v.x);
  out[i + 1] = __float2bfloat16(v.y);
  out[i + 2] = __float2bfloat16(v.z);
  out[i + 3] = __float2bfloat16(v.w);
}

// LN over D per (b,s) row of x -> bf16 (float4 loads, 8B packed stores)
__global__ __launch_bounds__(256) void ln1_kernel(const float* __restrict__ x,
    const float* __restrict__ g, const float* __restrict__ b, bf16* __restrict__ out) {
  __shared__ float sm4[4];
  long r = blockIdx.x;
  const float* row = x + r * Dh;
  int i0 = threadIdx.x * 4, i1 = 1024 + threadIdx.x * 4;
  float4 v0 = *(const float4*)(row + i0);
  float4 v1 = *(const float4*)(row + i1);
  float s = v0.x + v0.y + v0.z + v0.w + v1.x + v1.y + v1.z + v1.w;
  float s2 = v0.x * v0.x + v0.y * v0.y + v0.z * v0.z + v0.w * v0.w +
             v1.x * v1.x + v1.y * v1.y + v1.z * v1.z + v1.w * v1.w;
  s = block_sum(s, sm4);
  s2 = block_sum(s2, sm4);
  float mean = s * (1.f / Dh);
  float rstd = rsqrtf(s2 * (1.f / Dh) - mean * mean + LNEPS);
  float4 g0 = *(const float4*)(g + i0);
  float4 g1 = *(const float4*)(g + i1);
  float4 b0 = *(const float4*)(b + i0);
  float4 b1 = *(const float4*)(b + i1);
  ushort4v u0, u1;
  u0[0] = bf_bits((v0.x - mean) * rstd * g0.x + b0.x);
  u0[1] = bf_bits((v0.y - mean) * rstd * g0.y + b0.y);
  u0[2] = bf_bits((v0.z - mean) * rstd * g0.z + b0.z);
  u0[3] = bf_bits((v0.w - mean) * rstd * g0.w + b0.w);
  u1[0] = bf_bits((v1.x - mean) * rstd * g1.x + b1.x);
  u1[1] = bf_bits((v1.y - mean) * rstd * g1.y + b1.y);
  u1[2] = bf_bits((v1.z - mean) * rstd * g1.z + b1.z);
  u1[3] = bf_bits((v1.w - mean) * rstd * g1.w + b1.w);
  *(ushort4v*)(out + r * Dh + i0) = u0;
  *(ushort4v*)(out + r * Dh + i1) = u1;
}

// outbd[b*D+d] += (1/S) * sum over an s-chunk of in[b,s,d]
__global__ __launch_bounds__(256) void meanrow_kernel(const bf16* __restrict__ in,
                                                      float* __restrict__ outbd) {
  int gid = blockIdx.x * 256 + threadIdx.x;
  int s0 = blockIdx.y * 128;
  long base = ((long)(gid >> 11) * Sh + s0) * Dh + (gid & 2047);
  float s = 0.f;
  for (int t = 0; t < 128; ++t) s += __bfloat162float(in[base + (long)t * Dh]);
  atomicAdd(&outbd[gid], s * (1.f / Sh));
}

// Per (n,i): LN prc row (bf16 input), add proto_w; n<3: dot with ctx ->
// routing; n==3: store ps3
__global__ __launch_bounds__(256) void route_kernel(
    const bf16* __restrict__ prc, const float* __restrict__ proto_w,
    const float* __restrict__ pln_g, const float* __restrict__ pln_b,
    const float* __restrict__ gate, const float* __restrict__ ctx,
    float* __restrict__ routing, float* __restrict__ ps3) {
  __shared__ float sm4[4];
  int i = blockIdx.x, n = blockIdx.y;
  long rb = ((long)n * Dh + i) * Dh;
  float v[8];
  float s = 0.f, s2 = 0.f;
#pragma unroll
  for (int c = 0; c < 8; ++c) {
    float t = __bfloat162float(prc[rb + threadIdx.x + c * 256]);
    v[c] = t; s += t; s2 += t * t;
  }
  s = block_sum(s, sm4);
  s2 = block_sum(s2, sm4);
  float mean = s * (1.f / Dh);
  float rstd = rsqrtf(s2 * (1.f / Dh) - mean * mean + LNEPS);
  if (n == 3) {
#pragma unroll
    for (int c = 0; c < 8; ++c) {
      int o = threadIdx.x + c * 256;
      float ps = proto_w[rb + o] + (v[c] - mean) * rstd * pln_g[3 * Dh + o] + pln_b[3 * Dh + o];
      ps3[(long)i * Dh + o] = ps;
    }
  } else {
    float acc[4] = {0.f, 0.f, 0.f, 0.f};
#pragma unroll
    for (int c = 0; c < 8; ++c) {
      int o = threadIdx.x + c * 256;
      float ps = proto_w[rb + o] + (v[c] - mean) * rstd * pln_g[n * Dh + o] + pln_b[n * Dh + o];
#pragma unroll
      for (int b = 0; b < 4; ++b) acc[b] += ps * ctx[b * Dh + o];
    }
    for (int b = 0; b < 4; ++b) {
      float r = block_sum(acc[b], sm4);
      if (threadIdx.x == 0)
        routing[(n * 4 + b) * Dh + i] = r * INV_SQRT_D + gate[n * Dh + i];
    }
  }
}

__global__ __launch_bounds__(256) void route_o_kernel(
    const float* __restrict__ ps3, const float* __restrict__ ctxo,
    const float* __restrict__ gate, float* __restrict__ routing) {
  __shared__ float sm4[4];
  int i = blockIdx.x;
  float acc[4] = {0.f, 0.f, 0.f, 0.f};
#pragma unroll
  for (int c = 0; c < 8; ++c) {
    int o = threadIdx.x + c * 256;
    float p = ps3[(long)i * Dh + o];
#pragma unroll
    for (int b = 0; b < 4; ++b) acc[b] += p * ctxo[b * Dh + o];
  }
  for (int b = 0; b < 4; ++b) {
    float r = block_sum(acc[b], sm4);
    if (threadIdx.x == 0)
      routing[(12 + b) * Dh + i] = r * INV_SQRT_D + gate[3 * Dh + i];
  }
}

__global__ __launch_bounds__(256) void masnorm_kernel(const float* __restrict__ rin,
                                                      float* __restrict__ gout) {
  __shared__ float sm4[4];
  long r = blockIdx.x;
  float m = 0.f;
#pragma unroll
  for (int c = 0; c < 8; ++c)
    m = fmaxf(m, fabsf(rin[r * Dh + threadIdx.x + c * 256]));
  m = block_max(m, sm4);
  float inv = 1.f / (m + 1e-9f);
#pragma unroll
  for (int c = 0; c < 8; ++c) {
    int o = threadIdx.x + c * 256;
    gout[r * Dh + o] = rin[r * Dh + o] * inv;
  }
}

__global__ __launch_bounds__(256) void rope_table_kernel(float* __restrict__ cosT,
                                                         float* __restrict__ sinT) {
  int idx = blockIdx.x * 256 + threadIdx.x;
  int t = idx >> 10, f = idx & 1023;
  float inv_freq = expf(-(float)f * (9.210340371976184f / 1024.f));
  float ang = (float)t * inv_freq;
  cosT[idx] = cosf(ang);
  sinT[idx] = sinf(ang);
}

// In-place RoPE on q and k (bf16), full hidden dim, rotate_half convention
__global__ __launch_bounds__(256) void rope_kernel(bf16* __restrict__ q, bf16* __restrict__ k,
    const int* __restrict__ pos, const float* __restrict__ cosT,
    const float* __restrict__ sinT) {
  long r = blockIdx.x;
  int s = (int)(r & (Sh - 1));
  int p = pos[s];
#pragma unroll
  for (int c = 0; c < 4; ++c) {
    int t = threadIdx.x + c * 256;
    float cv = cosT[(long)p * HALF + t];
    float sv = sinT[(long)p * HALF + t];
    long i1 = r * Dh + t, i2 = i1 + HALF;
    float q1 = __bfloat162float(q[i1]), q2 = __bfloat162float(q[i2]);
    q[i1] = __float2bfloat16(q1 * cv - q2 * sv);
    q[i2] = __float2bfloat16(q2 * cv + q1 * sv);
    float k1 = __bfloat162float(k[i1]), k2 = __bfloat162float(k[i2]);
    k[i1] = __float2bfloat16(k1 * cv - k2 * sv);
    k[i2] = __float2bfloat16(k2 * cv + k1 * sv);
  }
}

// causal row softmax: f16 scores (vectorized), bf16 probs; zero-fill only
// up to the 128-boundary that PV actually reads.
__global__ __launch_bounds__(256) void softmax_kernel(const unsigned short* __restrict__ scores,
                                                      bf16* __restrict__ probs) {
  __shared__ float buf[Sh];
  __shared__ float sm4[4];
  long r = blockIdx.x;
  int qi = (int)(r & (Sh - 1));
  const unsigned short* row = scores + r * (long)Sh;
  bf16* prow = probs + r * (long)Sh;
  int tid = threadIdx.x;
  int n = qi + 1, nv = n & ~7;
  float m = -3.0e38f;
  for (int o = tid * 8; o < nv; o += 2048) {
    ushort8v v = *(const ushort8v*)(row + o);
#pragma unroll
    for (int j = 0; j < 8; ++j) {
      float x = h2f_bits(v[j]);
      buf[o + j] = x;
      m = fmaxf(m, x);
    }
  }
  for (int o = nv + tid; o < n; o += 256) {
    float x = h2f_bits(row[o]); buf[o] = x; m = fmaxf(m, x);
  }
  m = block_max(m, sm4);
  float s = 0.f;
  for (int o = tid; o < n; o += 256) {
    float e = __expf(buf[o] - m); buf[o] = e; s += e;
  }
  s = block_sum(s, sm4);
  float inv = 1.f / s;
  for (int o = tid * 8; o < nv; o += 2048) {
    ushort8v u;
#pragma unroll
    for (int j = 0; j < 8; ++j) u[j] = bf_bits(buf[o + j] * inv);
    *(ushort8v*)(prow + o) = u;
  }
  for (int o = nv + tid; o < n; o += 256) prow[o] = __float2bfloat16(buf[o] * inv);
  int zlim = (qi & ~127) + 128;  // PV reads k < zlim only
  int za = (n + 7) & ~7;
  for (int o = n + tid; o < za && o < zlim; o += 256) prow[o] = __float2bfloat16(0.f);
  ushort8v zz = {0, 0, 0, 0, 0, 0, 0, 0};
  for (int o = za + tid * 8; o < zlim; o += 2048) *(ushort8v*)(prow + o) = zz;
}

extern "C" void kernel_launch(void* const* d_in, const int* in_sizes, int n_in,
                              void* d_out, int out_size, void* d_ws, size_t ws_size,
                              hipStream_t stream) {
  const float* x       = (const float*)d_in[0];
  const int*   pos     = (const int*)d_in[1];
  const float* ln1_g   = (const float*)d_in[2];
  const float* ln1_b   = (const float*)d_in[3];
  const float* mu_w    = (const float*)d_in[4];
  const float* mu_b    = (const float*)d_in[5];
  const float* proto_w = (const float*)d_in[6];
  const float* gate    = (const float*)d_in[7];
  const float* pt_w    = (const float*)d_in[8];
  const float* pln_g   = (const float*)d_in[9];
  const float* pln_b   = (const float*)d_in[10];
  const float* incoming= (const float*)d_in[11];

  // workspace layout (~302 MB); prc bf16 / f16 scores live in d_out
  char* w = (char*)d_ws;
  const long BF = 33554432L;  // bytes of one bf16 [8192][2048]
  bf16*  ln1    = (bf16*)(w);
  bf16*  qb     = (bf16*)(w + BF);
  bf16*  kb     = (bf16*)(w + 2 * BF);
  bf16*  vb     = (bf16*)(w + 3 * BF);   // unused (V written transposed)
  bf16*  attn   = (bf16*)(w + 4 * BF);
  bf16*  mu_wb  = (bf16*)(w + 5 * BF);         // [4][D][D] bf16
  bf16*  ptw_b  = (bf16*)(w + 6 * BF);         // aliased: later vT [4][D][S]
  bf16*  vT     = ptw_b;
  bf16*  inc_b  = (bf16*)(w + 7 * BF);         // aliased: later probs [4][S][S]
  bf16*  probs  = inc_b;
  float* ps3    = (float*)(w + 8 * BF);                 // [2048][2048] f32
  float* cosT   = (float*)(w + 8 * BF + 16777216L);
  float* sinT   = cosT + (long)Sh * HALF;
  float* ctx    = sinT + (long)Sh * HALF;               // [4][2048]
  float* ctxo   = ctx + Bh * Dh;
  float* routing= ctxo + Bh * Dh;                       // [16][2048]
  float* gating = routing + 16 * Dh;                    // [16][2048]
  bf16*   prc    = (bf16*)d_out;                        // bf16 [4][2048][2048]
  __half* scores = (__half*)d_out;                      // f16 [4][2048][2048]
  (void)vb;

  const long DD4 = 4L * Dh * Dh;

  hipMemsetAsync(ctx, 0, 2L * Bh * Dh * sizeof(float), stream);

  rope_table_kernel<<<(Sh * HALF) / 256, 256, 0, stream>>>(cosT, sinT);
  cvt3_kernel<<<dim3(DD4 / 1024, 3), 256, 0, stream>>>(
      mu_w, incoming, pt_w, mu_wb, inc_b, ptw_b, DD4);
  ln1_kernel<<<NROW, 256, 0, stream>>>(x, ln1_g, ln1_b, ln1);
  meanrow_kernel<<<dim3(32, 16), 256, 0, stream>>>(ln1, ctx);
  // prc[n] = incoming[n] @ pt_w[n]^T  -> prc (bf16, in d_out)
  pgemm<0><<<dim3(8, 8, 4), 512, 0, stream>>>(
      inc_b, ptw_b, prc, Dh, Dh, Dh, Dh,
      (long)Dh * Dh, (long)Dh * Dh, (long)Dh * Dh,
      nullptr, nullptr, nullptr, nullptr);
  route_kernel<<<dim3(Dh, 4), 256, 0, stream>>>(prc, proto_w, pln_g, pln_b,
                                                gate, ctx, routing, ps3);
  masnorm_kernel<<<12, 256, 0, stream>>>(routing, gating);
  // q/k/v = gating * silu(ln1 @ mu_w[n]^T + mu_b[n]); v written TRANSPOSED
  pgemm<1><<<dim3(32, 8, 3), 512, 0, stream>>>(
      ln1, mu_wb, qb, Dh, Dh, Dh, Dh,
      0L, (long)Dh * Dh, (long)NROW * Dh, mu_b, gating, nullptr, vT);
  rope_kernel<<<NROW, 256, 0, stream>>>(qb, kb, pos, cosT, sinT);
  // scores = q @ k^T * inv_sqrt_d (causal blocks only) -> f16
  pgemm<2><<<dim3(8, 8, 4), 512, 0, stream>>>(
      qb, kb, scores, Sh, Dh, Dh, Dh,
      (long)Sh * Dh, (long)Sh * Dh, (long)Sh * Sh,
      nullptr, nullptr, nullptr, nullptr);
  softmax_kernel<<<Bh * Sh, 256, 0, stream>>>((const unsigned short*)scores, probs);
  // attn = probs @ vT^T  (balanced causal kernel)
  pgemm_h<<<512, 512, 0, stream>>>(
      probs, vT, attn, Dh, Sh, Sh,
      (long)Sh * Sh, (long)Dh * Sh, (long)Sh * Dh);
  meanrow_kernel<<<dim3(32, 16), 256, 0, stream>>>(attn, ctxo);
  route_o_kernel<<<Dh, 256, 0, stream>>>(ps3, ctxo, gate, routing);
  masnorm_kernel<<<4, 256, 0, stream>>>(routing + 12 * Dh, gating + 12 * Dh);
  // out = x + gating_o * silu(attn @ mu_w[3]^T + mu_b[3])
  pgemm<4><<<dim3(32, 8, 1), 512, 0, stream>>>(
      attn, mu_wb + 3L * Dh * Dh, d_out, Dh, Dh, Dh, Dh,
      0L, 0L, 0L, mu_b + 3 * Dh, gating + 12 * Dh, x, nullptr);
}

// Round 25
// 601.090 us; speedup vs baseline: 1.0698x; 1.0698x over previous
//
#include <hip/hip_runtime.h>
#include <hip/hip_bf16.h>
#include <hip/hip_fp16.h>

#define Dh 2048
#define Bh 4
#define Sh 2048
#define NROW 8192          // B*S
#define HALF 1024
#define INV_SQRT_D 0.022097086912079608f
#define LNEPS 1e-5f

typedef __hip_bfloat16 bf16;
typedef short short8 __attribute__((ext_vector_type(8)));
typedef float f32x4 __attribute__((ext_vector_type(4)));
typedef unsigned short ushort8v __attribute__((ext_vector_type(8)));
typedef unsigned short ushort4v __attribute__((ext_vector_type(4)));

__device__ inline float h2f_bits(unsigned short u) {
  __half h;
  *(unsigned short*)&h = u;
  return __half2float(h);
}
__device__ inline unsigned short bf_bits(float f) {
  bf16 t = __float2bfloat16(f);
  return *(unsigned short*)&t;
}

__device__ inline float warp_sum(float x) {
#pragma unroll
  for (int o = 32; o > 0; o >>= 1) x += __shfl_down(x, o);
  return x;
}
__device__ inline float warp_max(float x) {
#pragma unroll
  for (int o = 32; o > 0; o >>= 1) x = fmaxf(x, __shfl_down(x, o));
  return x;
}
__device__ inline float block_sum(float x, float* sm4) {
  x = warp_sum(x);
  int w = threadIdx.x >> 6;
  if ((threadIdx.x & 63) == 0) sm4[w] = x;
  __syncthreads();
  float r = sm4[0] + sm4[1] + sm4[2] + sm4[3];
  __syncthreads();
  return r;
}
__device__ inline float block_max(float x, float* sm4) {
  x = warp_max(x);
  int w = threadIdx.x >> 6;
  if ((threadIdx.x & 63) == 0) sm4[w] = x;
  __syncthreads();
  float r = fmaxf(fmaxf(sm4[0], sm4[1]), fmaxf(sm4[2], sm4[3]));
  __syncthreads();
  return r;
}

// async global->LDS, 16B per lane; LDS dest is wave-uniform base + lane*16
__device__ inline void gload_lds16(const void* g, void* lds) {
  __builtin_amdgcn_global_load_lds(
      (const __attribute__((address_space(1))) unsigned int*)(unsigned long long)g,
      (__attribute__((address_space(3))) unsigned int*)(unsigned long long)lds,
      16, 0, 0);
}

#define MM4(R, AF, B0, B1, B2, B3)                                             \
  acc[R][0] = __builtin_amdgcn_mfma_f32_16x16x32_bf16(AF, B0, acc[R][0], 0, 0, 0); \
  acc[R][1] = __builtin_amdgcn_mfma_f32_16x16x32_bf16(AF, B1, acc[R][1], 0, 0, 0); \
  acc[R][2] = __builtin_amdgcn_mfma_f32_16x16x32_bf16(AF, B2, acc[R][2], 0, 0, 0); \
  acc[R][3] = __builtin_amdgcn_mfma_f32_16x16x32_bf16(AF, B3, acc[R][3], 0, 0, 0);

// ---------------------------------------------------------------------------
// MFMA bf16 GEMM (R18 structure, validated best; R24's 4-phase cadence
// regressed 202->233us and is reverted -- cadence lever conclusively
// falsified on this family after 2 faithful attempts):
// C[M,N] = A[M,K] @ B[N,K]^T. 256x256 tile, BK=64, 16x16x32 MFMA, 8 waves
// (2Mx4N), per-wave 128x64. LDS 160KB: A 2x32KB (t&1) + B 3x32KB (t%3).
// ONE barrier per tile. Race/vmcnt ledgers as R18 (validated 6 rounds).
// MODE 1 z==2 (V): LDS-staged transposed epilogue (R21, validated).
// MODE 0: C bf16 = acc (prc)
// MODE 1: C bf16 = silu(acc + e0[z*D+c]) * e1[(z*4+b)*D+c]; z==2 -> vt
// MODE 2: C f16 = acc*INV_SQRT_D, skip blocks above causal diagonal (QK^T)
// MODE 4: C f32 = x + gating_o * silu(acc + mu_b3)  (o-proj + residual)
// ---------------------------------------------------------------------------
template <int MODE>
__global__ __launch_bounds__(512) void pgemm(
    const bf16* __restrict__ Aall, const bf16* __restrict__ Ball,
    void* __restrict__ Call, int N, int K, int lda, int ldb,
    long sAz, long sBz, long sCz,
    const float* __restrict__ e0, const float* __restrict__ e1,
    const float* __restrict__ e2, bf16* __restrict__ vt) {
  const int bm0 = blockIdx.x * 256;
  const int bn0 = blockIdx.y * 256;
  if (MODE == 2 && bn0 > bm0 + 255) return;  // fully above causal diagonal
  const int z = blockIdx.z;
  const bf16* A = Aall + (long)z * sAz;
  const bf16* B = Ball + (long)z * sBz;

  __shared__ __align__(16) char smem[163840];  // A 2x32K | B 3x32K @65536
  const int tid = threadIdx.x;
  const int l = tid & 63, w = tid >> 6;
  const int wr = w >> 2, wc = w & 3;  // wave grid 2x4

  f32x4 acc[8][4] = {};
  const int nt = K >> 6;

  const int sg = (((l & 7) ^ ((l >> 3) & 7)) << 3);  // pre-swizzled granule
  const int srow = (w << 3) + (l >> 3);
  const bf16* aS0 = A + (long)(bm0 + srow) * lda + sg;
  const bf16* aS1 = A + (long)(bm0 + 64 + srow) * lda + sg;
  const bf16* aS2 = A + (long)(bm0 + 128 + srow) * lda + sg;
  const bf16* aS3 = A + (long)(bm0 + 192 + srow) * lda + sg;
  const bf16* bT0 = B + (long)(bn0 + srow) * ldb + sg;
  const bf16* bT1 = B + (long)(bn0 + 64 + srow) * ldb + sg;
  const bf16* bT2 = B + (long)(bn0 + 128 + srow) * ldb + sg;
  const bf16* bT3 = B + (long)(bn0 + 192 + srow) * ldb + sg;
  char* const dA = smem + (w << 10);
  char* const dB = smem + 65536 + (w << 10);

  auto stageA = [&](int tt) {
    int boff = (tt & 1) << 15;
    gload_lds16(aS0 + (tt << 6), dA + boff);
    gload_lds16(aS1 + (tt << 6), dA + boff + 8192);
    gload_lds16(aS2 + (tt << 6), dA + boff + 16384);
    gload_lds16(aS3 + (tt << 6), dA + boff + 24576);
  };
  auto stageB = [&](int tt) {
    int boff = (tt % 3) << 15;
    gload_lds16(bT0 + (tt << 6), dB + boff);
    gload_lds16(bT1 + (tt << 6), dB + boff + 8192);
    gload_lds16(bT2 + (tt << 6), dB + boff + 16384);
    gload_lds16(bT3 + (tt << 6), dB + boff + 24576);
  };

  stageA(0); stageB(0);
  if (nt > 1) stageB(1);
  if (nt > 1) asm volatile("s_waitcnt vmcnt(4)" ::: "memory");
  else        asm volatile("s_waitcnt vmcnt(0)" ::: "memory");
  __builtin_amdgcn_sched_barrier(0);
  asm volatile("s_barrier" ::: "memory");

  const int rslot = (((l >> 4) ^ (l & 7)) << 4);
  const int abyte = (((wr << 7) + (l & 15)) << 7) + rslot;
  const int bbyte = (((wc << 6) + (l & 15)) << 7) + rslot;

  for (int t = 0; t < nt; ++t) {
    const char* Ab = smem + ((t & 1) << 15);
    const char* Bb = smem + 65536 + ((t % 3) << 15);
    short8 b00 = *(const short8*)(Bb + bbyte);
    short8 b01 = *(const short8*)(Bb + bbyte + 2048);
    short8 b02 = *(const short8*)(Bb + bbyte + 4096);
    short8 b03 = *(const short8*)(Bb + bbyte + 6144);
    short8 b10 = *(const short8*)(Bb + (bbyte ^ 64));
    short8 b11 = *(const short8*)(Bb + ((bbyte + 2048) ^ 64));
    short8 b12 = *(const short8*)(Bb + ((bbyte + 4096) ^ 64));
    short8 b13 = *(const short8*)(Bb + ((bbyte + 6144) ^ 64));
    short8 a0 = *(const short8*)(Ab + abyte);
    short8 a1 = *(const short8*)(Ab + abyte + 2048);
    short8 a2 = *(const short8*)(Ab + abyte + 4096);
    short8 a3 = *(const short8*)(Ab + abyte + 6144);
    short8 a4 = *(const short8*)(Ab + abyte + 8192);
    short8 a5 = *(const short8*)(Ab + abyte + 10240);
    short8 a6 = *(const short8*)(Ab + abyte + 12288);
    short8 a7 = *(const short8*)(Ab + abyte + 14336);
    if (t + 1 < nt) stageA(t + 1);
    MM4(0, a0, b00, b01, b02, b03) MM4(1, a1, b00, b01, b02, b03)
    MM4(2, a2, b00, b01, b02, b03) MM4(3, a3, b00, b01, b02, b03)
    MM4(4, a4, b00, b01, b02, b03) MM4(5, a5, b00, b01, b02, b03)
    MM4(6, a6, b00, b01, b02, b03) MM4(7, a7, b00, b01, b02, b03)
    short8 c0 = *(const short8*)(Ab + (abyte ^ 64));
    short8 c1 = *(const short8*)(Ab + ((abyte + 2048) ^ 64));
    short8 c2 = *(const short8*)(Ab + ((abyte + 4096) ^ 64));
    short8 c3 = *(const short8*)(Ab + ((abyte + 6144) ^ 64));
    short8 c4 = *(const short8*)(Ab + ((abyte + 8192) ^ 64));
    short8 c5 = *(const short8*)(Ab + ((abyte + 10240) ^ 64));
    short8 c6 = *(const short8*)(Ab + ((abyte + 12288) ^ 64));
    short8 c7 = *(const short8*)(Ab + ((abyte + 14336) ^ 64));
    if (t + 2 < nt) stageB(t + 2);
    MM4(0, c0, b10, b11, b12, b13) MM4(1, c1, b10, b11, b12, b13)
    MM4(2, c2, b10, b11, b12, b13) MM4(3, c3, b10, b11, b12, b13)
    MM4(4, c4, b10, b11, b12, b13) MM4(5, c5, b10, b11, b12, b13)
    MM4(6, c6, b10, b11, b12, b13) MM4(7, c7, b10, b11, b12, b13)
    if (t < nt - 1) {
      asm volatile("s_waitcnt lgkmcnt(0)" ::: "memory");
      if (t + 2 < nt) asm volatile("s_waitcnt vmcnt(4)" ::: "memory");
      else            asm volatile("s_waitcnt vmcnt(0)" ::: "memory");
      __builtin_amdgcn_sched_barrier(0);
      asm volatile("s_barrier" ::: "memory");
    }
  }

  // epilogue: C/D mapping col = lane&15, row = (lane>>4)*4 + reg
  const int lc = l & 15, lr4 = (l >> 4) << 2;
  if (MODE == 1 && z == 2) {
    // V: LDS-staged transpose. Padded [col][264] ushort tile (135KB).
    unsigned short* tl = (unsigned short*)smem;
    const int bb = bm0 >> 11, s0r = bm0 & 2047;
    __syncthreads();  // all waves done reading staged A/B
#pragma unroll
    for (int fr = 0; fr < 8; ++fr) {
      int row0 = (wr << 7) + fr * 16 + lr4;
#pragma unroll
      for (int fc = 0; fc < 4; ++fc) {
        int col = (wc << 6) + fc * 16 + lc;
        int gc = bn0 + col;
        ushort4v u;
#pragma unroll
        for (int qv = 0; qv < 4; ++qv) {
          float val = acc[fr][fc][qv] + e0[2 * Dh + gc];
          float sil = val / (1.f + __expf(-val));
          u[qv] = bf_bits(sil * e1[(2 * Bh + bb) * Dh + gc]);
        }
        *(ushort4v*)(tl + col * 264 + row0) = u;
      }
    }
    __syncthreads();
#pragma unroll
    for (int it = 0; it < 4; ++it) {
      int idx = tid + it * 512;
      int col = idx >> 3, ch = idx & 7;
      const ushort8v* src = (const ushort8v*)(tl + col * 264 + ch * 32);
      ushort8v v0 = src[0], v1 = src[1], v2 = src[2], v3 = src[3];
      ushort8v* dst = (ushort8v*)((unsigned short*)vt +
          ((long)bb * Dh + bn0 + col) * Sh + s0r + ch * 32);
      dst[0] = v0; dst[1] = v1; dst[2] = v2; dst[3] = v3;
    }
  } else {
#pragma unroll
    for (int fr = 0; fr < 8; ++fr) {
      int gr0 = bm0 + (wr << 7) + fr * 16 + lr4;
#pragma unroll
      for (int fc = 0; fc < 4; ++fc) {
        int gc = bn0 + (wc << 6) + fc * 16 + lc;
#pragma unroll
        for (int qv = 0; qv < 4; ++qv) {
          int gr = gr0 + qv;
          float a = acc[fr][fc][qv];
          if (MODE == 0) {
            ((bf16*)Call + (long)z * sCz)[(long)gr * N + gc] =
                __float2bfloat16(a);
          } else if (MODE == 1) {
            float val = a + e0[z * Dh + gc];
            float sil = val / (1.f + __expf(-val));
            int bb = gr >> 11;
            float g = e1[(z * Bh + bb) * Dh + gc];
            ((bf16*)Call + (long)z * sCz)[(long)gr * N + gc] =
                __float2bfloat16(sil * g);
          } else if (MODE == 2) {
            ((__half*)Call + (long)z * sCz)[(long)gr * N + gc] =
                __float2half(a * INV_SQRT_D);
          } else {
            float val = a + e0[gc];
            float sil = val / (1.f + __expf(-val));
            int bb = gr >> 11;
            ((float*)Call)[(long)gr * N + gc] =
                e2[(long)gr * N + gc] + e1[bb * Dh + gc] * sil;
          }
        }
      }
    }
  }
}

// ---------------------------------------------------------------------------
// Balanced causal PV GEMM (R19 structure, validated): attn = probs @ vT^T.
// BK=64, BM=128, BN=256, 8 waves 2x4, per-wave 64x64. LDS 128KB.
// One barrier per tile. 512 blocks, complementary remap.
// ---------------------------------------------------------------------------
__global__ __launch_bounds__(512) void pgemm_h(
    const bf16* __restrict__ Aall, const bf16* __restrict__ Ball,
    bf16* __restrict__ Call, int N, int lda, int ldb,
    long sAz, long sBz, long sCz) {
  const int fid = blockIdx.x;
  const int p = fid >> 8, q = fid & 255;
  const int mh = q >> 5;
  const int z = (q >> 3) & 3, ni = q & 7;
  const int mi = p ? (15 - mh) : mh;
  const int bm0 = mi * 128, bn0 = ni * 256;
  const bf16* A = Aall + (long)z * sAz;
  const bf16* B = Ball + (long)z * sBz;

  __shared__ __align__(16) char smem[131072];  // A 2x16K | B 3x32K @32768
  const int tid = threadIdx.x;
  const int l = tid & 63, w = tid >> 6;
  const int wr = w >> 2, wc = w & 3;
  f32x4 acc[4][4] = {};
  const int nt = (bm0 + 128) >> 6;  // 2..32

  const int sg = (((l & 7) ^ ((l >> 3) & 7)) << 3);
  const int srow = (w << 3) + (l >> 3);
  const bf16* aS0 = A + (long)(bm0 + srow) * lda + sg;
  const bf16* aS1 = A + (long)(bm0 + 64 + srow) * lda + sg;
  const bf16* bT0 = B + (long)(bn0 + srow) * ldb + sg;
  const bf16* bT1 = B + (long)(bn0 + 64 + srow) * ldb + sg;
  const bf16* bT2 = B + (long)(bn0 + 128 + srow) * ldb + sg;
  const bf16* bT3 = B + (long)(bn0 + 192 + srow) * ldb + sg;
  char* const dA = smem + (w << 10);
  char* const dB = smem + 32768 + (w << 10);

  auto stageA = [&](int tt) {
    int boff = (tt & 1) << 14;
    gload_lds16(aS0 + (tt << 6), dA + boff);
    gload_lds16(aS1 + (tt << 6), dA + boff + 8192);
  };
  auto stageB = [&](int tt) {
    int boff = (tt % 3) << 15;
    gload_lds16(bT0 + (tt << 6), dB + boff);
    gload_lds16(bT1 + (tt << 6), dB + boff + 8192);
    gload_lds16(bT2 + (tt << 6), dB + boff + 16384);
    gload_lds16(bT3 + (tt << 6), dB + boff + 24576);
  };

  stageA(0); stageB(0); stageB(1);   // nt >= 2 always
  asm volatile("s_waitcnt vmcnt(4)" ::: "memory");
  __builtin_amdgcn_sched_barrier(0);
  asm volatile("s_barrier" ::: "memory");

  const int rslot = (((l >> 4) ^ (l & 7)) << 4);
  const int abyte = (((wr << 6) + (l & 15)) << 7) + rslot;
  const int bbyte = (((wc << 6) + (l & 15)) << 7) + rslot;

  for (int t = 0; t < nt; ++t) {
    const char* Ab = smem + ((t & 1) << 14);
    const char* Bb = smem + 32768 + ((t % 3) << 15);
    short8 b00 = *(const short8*)(Bb + bbyte);
    short8 b01 = *(const short8*)(Bb + bbyte + 2048);
    short8 b02 = *(const short8*)(Bb + bbyte + 4096);
    short8 b03 = *(const short8*)(Bb + bbyte + 6144);
    short8 b10 = *(const short8*)(Bb + (bbyte ^ 64));
    short8 b11 = *(const short8*)(Bb + ((bbyte + 2048) ^ 64));
    short8 b12 = *(const short8*)(Bb + ((bbyte + 4096) ^ 64));
    short8 b13 = *(const short8*)(Bb + ((bbyte + 6144) ^ 64));
    short8 a0 = *(const short8*)(Ab + abyte);
    short8 a1 = *(const short8*)(Ab + abyte + 2048);
    short8 a2 = *(const short8*)(Ab + abyte + 4096);
    short8 a3 = *(const short8*)(Ab + abyte + 6144);
    if (t + 1 < nt) stageA(t + 1);
    MM4(0, a0, b00, b01, b02, b03) MM4(1, a1, b00, b01, b02, b03)
    MM4(2, a2, b00, b01, b02, b03) MM4(3, a3, b00, b01, b02, b03)
    short8 c0 = *(const short8*)(Ab + (abyte ^ 64));
    short8 c1 = *(const short8*)(Ab + ((abyte + 2048) ^ 64));
    short8 c2 = *(const short8*)(Ab + ((abyte + 4096) ^ 64));
    short8 c3 = *(const short8*)(Ab + ((abyte + 6144) ^ 64));
    if (t + 2 < nt) stageB(t + 2);
    MM4(0, c0, b10, b11, b12, b13) MM4(1, c1, b10, b11, b12, b13)
    MM4(2, c2, b10, b11, b12, b13) MM4(3, c3, b10, b11, b12, b13)
    if (t < nt - 1) {
      asm volatile("s_waitcnt lgkmcnt(0)" ::: "memory");
      if (t + 2 < nt) asm volatile("s_waitcnt vmcnt(4)" ::: "memory");
      else            asm volatile("s_waitcnt vmcnt(0)" ::: "memory");
      __builtin_amdgcn_sched_barrier(0);
      asm volatile("s_barrier" ::: "memory");
    }
  }

  const int lc = l & 15, lr4 = (l >> 4) << 2;
  bf16* C = Call + (long)z * sCz;
#pragma unroll
  for (int fr = 0; fr < 4; ++fr) {
    int gr0 = bm0 + (wr << 6) + fr * 16 + lr4;
#pragma unroll
    for (int fc = 0; fc < 4; ++fc) {
      int gc = bn0 + (wc << 6) + fc * 16 + lc;
#pragma unroll
      for (int qv = 0; qv < 4; ++qv)
        C[(long)(gr0 + qv) * N + gc] = __float2bfloat16(acc[fr][fc][qv]);
    }
  }
}

// f32 -> bf16 elementwise for 3 tensors of DD4 elements each (y selects)
__global__ __launch_bounds__(256) void cvt3_kernel(
    const float* __restrict__ s0, const float* __restrict__ s1,
    const float* __restrict__ s2, bf16* __restrict__ o0, bf16* __restrict__ o1,
    bf16* __restrict__ o2, long n) {
  const float* in = (blockIdx.y == 0) ? s0 : (blockIdx.y == 1) ? s1 : s2;
  bf16* out = (blockIdx.y == 0) ? o0 : (blockIdx.y == 1) ? o1 : o2;
  long i = ((long)blockIdx.x * 256 + threadIdx.x) * 4;
  if (i >= n) return;
  float4 v = *(const float4*)(in + i);
  out[i + 0] = __float2bfloat16(v.x);
  out[i + 1] = __float2bfloat16(v.y);
  out[i + 2] = __float2bfloat16(v.z);
  out[i + 3] = __float2bfloat16(v.w);
}

// LN over D per (b,s) row of x -> bf16 (float4 loads, 8B packed stores)
__global__ __launch_bounds__(256) void ln1_kernel(const float* __restrict__ x,
    const float* __restrict__ g, const float* __restrict__ b, bf16* __restrict__ out) {
  __shared__ float sm4[4];
  long r = blockIdx.x;
  const float* row = x + r * Dh;
  int i0 = threadIdx.x * 4, i1 = 1024 + threadIdx.x * 4;
  float4 v0 = *(const float4*)(row + i0);
  float4 v1 = *(const float4*)(row + i1);
  float s = v0.x + v0.y + v0.z + v0.w + v1.x + v1.y + v1.z + v1.w;
  float s2 = v0.x * v0.x + v0.y * v0.y + v0.z * v0.z + v0.w * v0.w +
             v1.x * v1.x + v1.y * v1.y + v1.z * v1.z + v1.w * v1.w;
  s = block_sum(s, sm4);
  s2 = block_sum(s2, sm4);
  float mean = s * (1.f / Dh);
  float rstd = rsqrtf(s2 * (1.f / Dh) - mean * mean + LNEPS);
  float4 g0 = *(const float4*)(g + i0);
  float4 g1 = *(const float4*)(g + i1);
  float4 b0 = *(const float4*)(b + i0);
  float4 b1 = *(const float4*)(b + i1);
  ushort4v u0, u1;
  u0[0] = bf_bits((v0.x - mean) * rstd * g0.x + b0.x);
  u0[1] = bf_bits((v0.y - mean) * rstd * g0.y + b0.y);
  u0[2] = bf_bits((v0.z - mean) * rstd * g0.z + b0.z);
  u0[3] = bf_bits((v0.w - mean) * rstd * g0.w + b0.w);
  u1[0] = bf_bits((v1.x - mean) * rstd * g1.x + b1.x);
  u1[1] = bf_bits((v1.y - mean) * rstd * g1.y + b1.y);
  u1[2] = bf_bits((v1.z - mean) * rstd * g1.z + b1.z);
  u1[3] = bf_bits((v1.w - mean) * rstd * g1.w + b1.w);
  *(ushort4v*)(out + r * Dh + i0) = u0;
  *(ushort4v*)(out + r * Dh + i1) = u1;
}

// outbd[b*D+d] += (1/S) * sum over an s-chunk of in[b,s,d]
__global__ __launch_bounds__(256) void meanrow_kernel(const bf16* __restrict__ in,
                                                      float* __restrict__ outbd) {
  int gid = blockIdx.x * 256 + threadIdx.x;
  int s0 = blockIdx.y * 128;
  long base = ((long)(gid >> 11) * Sh + s0) * Dh + (gid & 2047);
  float s = 0.f;
  for (int t = 0; t < 128; ++t) s += __bfloat162float(in[base + (long)t * Dh]);
  atomicAdd(&outbd[gid], s * (1.f / Sh));
}

// Per (n,i): LN prc row (bf16 input), add proto_w; n<3: dot with ctx ->
// routing; n==3: store ps3
__global__ __launch_bounds__(256) void route_kernel(
    const bf16* __restrict__ prc, const float* __restrict__ proto_w,
    const float* __restrict__ pln_g, const float* __restrict__ pln_b,
    const float* __restrict__ gate, const float* __restrict__ ctx,
    float* __restrict__ routing, float* __restrict__ ps3) {
  __shared__ float sm4[4];
  int i = blockIdx.x, n = blockIdx.y;
  long rb = ((long)n * Dh + i) * Dh;
  float v[8];
  float s = 0.f, s2 = 0.f;
#pragma unroll
  for (int c = 0; c < 8; ++c) {
    float t = __bfloat162float(prc[rb + threadIdx.x + c * 256]);
    v[c] = t; s += t; s2 += t * t;
  }
  s = block_sum(s, sm4);
  s2 = block_sum(s2, sm4);
  float mean = s * (1.f / Dh);
  float rstd = rsqrtf(s2 * (1.f / Dh) - mean * mean + LNEPS);
  if (n == 3) {
#pragma unroll
    for (int c = 0; c < 8; ++c) {
      int o = threadIdx.x + c * 256;
      float ps = proto_w[rb + o] + (v[c] - mean) * rstd * pln_g[3 * Dh + o] + pln_b[3 * Dh + o];
      ps3[(long)i * Dh + o] = ps;
    }
  } else {
    float acc[4] = {0.f, 0.f, 0.f, 0.f};
#pragma unroll
    for (int c = 0; c < 8; ++c) {
      int o = threadIdx.x + c * 256;
      float ps = proto_w[rb + o] + (v[c] - mean) * rstd * pln_g[n * Dh + o] + pln_b[n * Dh + o];
#pragma unroll
      for (int b = 0; b < 4; ++b) acc[b] += ps * ctx[b * Dh + o];
    }
    for (int b = 0; b < 4; ++b) {
      float r = block_sum(acc[b], sm4);
      if (threadIdx.x == 0)
        routing[(n * 4 + b) * Dh + i] = r * INV_SQRT_D + gate[n * Dh + i];
    }
  }
}

__global__ __launch_bounds__(256) void route_o_kernel(
    const float* __restrict__ ps3, const float* __restrict__ ctxo,
    const float* __restrict__ gate, float* __restrict__ routing) {
  __shared__ float sm4[4];
  int i = blockIdx.x;
  float acc[4] = {0.f, 0.f, 0.f, 0.f};
#pragma unroll
  for (int c = 0; c < 8; ++c) {
    int o = threadIdx.x + c * 256;
    float p = ps3[(long)i * Dh + o];
#pragma unroll
    for (int b = 0; b < 4; ++b) acc[b] += p * ctxo[b * Dh + o];
  }
  for (int b = 0; b < 4; ++b) {
    float r = block_sum(acc[b], sm4);
    if (threadIdx.x == 0)
      routing[(12 + b) * Dh + i] = r * INV_SQRT_D + gate[3 * Dh + i];
  }
}

__global__ __launch_bounds__(256) void masnorm_kernel(const float* __restrict__ rin,
                                                      float* __restrict__ gout) {
  __shared__ float sm4[4];
  long r = blockIdx.x;
  float m = 0.f;
#pragma unroll
  for (int c = 0; c < 8; ++c)
    m = fmaxf(m, fabsf(rin[r * Dh + threadIdx.x + c * 256]));
  m = block_max(m, sm4);
  float inv = 1.f / (m + 1e-9f);
#pragma unroll
  for (int c = 0; c < 8; ++c) {
    int o = threadIdx.x + c * 256;
    gout[r * Dh + o] = rin[r * Dh + o] * inv;
  }
}

__global__ __launch_bounds__(256) void rope_table_kernel(float* __restrict__ cosT,
                                                         float* __restrict__ sinT) {
  int idx = blockIdx.x * 256 + threadIdx.x;
  int t = idx >> 10, f = idx & 1023;
  float inv_freq = expf(-(float)f * (9.210340371976184f / 1024.f));
  float ang = (float)t * inv_freq;
  cosT[idx] = cosf(ang);
  sinT[idx] = sinf(ang);
}

// In-place RoPE on q and k (bf16), full hidden dim, rotate_half convention
__global__ __launch_bounds__(256) void rope_kernel(bf16* __restrict__ q, bf16* __restrict__ k,
    const int* __restrict__ pos, const float* __restrict__ cosT,
    const float* __restrict__ sinT) {
  long r = blockIdx.x;
  int s = (int)(r & (Sh - 1));
  int p = pos[s];
#pragma unroll
  for (int c = 0; c < 4; ++c) {
    int t = threadIdx.x + c * 256;
    float cv = cosT[(long)p * HALF + t];
    float sv = sinT[(long)p * HALF + t];
    long i1 = r * Dh + t, i2 = i1 + HALF;
    float q1 = __bfloat162float(q[i1]), q2 = __bfloat162float(q[i2]);
    q[i1] = __float2bfloat16(q1 * cv - q2 * sv);
    q[i2] = __float2bfloat16(q2 * cv + q1 * sv);
    float k1 = __bfloat162float(k[i1]), k2 = __bfloat162float(k[i2]);
    k[i1] = __float2bfloat16(k1 * cv - k2 * sv);
    k[i2] = __float2bfloat16(k2 * cv + k1 * sv);
  }
}

// causal row softmax: f16 scores (vectorized), bf16 probs; zero-fill only
// up to the 128-boundary that PV actually reads.
__global__ __launch_bounds__(256) void softmax_kernel(const unsigned short* __restrict__ scores,
                                                      bf16* __restrict__ probs) {
  __shared__ float buf[Sh];
  __shared__ float sm4[4];
  long r = blockIdx.x;
  int qi = (int)(r & (Sh - 1));
  const unsigned short* row = scores + r * (long)Sh;
  bf16* prow = probs + r * (long)Sh;
  int tid = threadIdx.x;
  int n = qi + 1, nv = n & ~7;
  float m = -3.0e38f;
  for (int o = tid * 8; o < nv; o += 2048) {
    ushort8v v = *(const ushort8v*)(row + o);
#pragma unroll
    for (int j = 0; j < 8; ++j) {
      float x = h2f_bits(v[j]);
      buf[o + j] = x;
      m = fmaxf(m, x);
    }
  }
  for (int o = nv + tid; o < n; o += 256) {
    float x = h2f_bits(row[o]); buf[o] = x; m = fmaxf(m, x);
  }
  m = block_max(m, sm4);
  float s = 0.f;
  for (int o = tid; o < n; o += 256) {
    float e = __expf(buf[o] - m); buf[o] = e; s += e;
  }
  s = block_sum(s, sm4);
  float inv = 1.f / s;
  for (int o = tid * 8; o < nv; o += 2048) {
    ushort8v u;
#pragma unroll
    for (int j = 0; j < 8; ++j) u[j] = bf_bits(buf[o + j] * inv);
    *(ushort8v*)(prow + o) = u;
  }
  for (int o = nv + tid; o < n; o += 256) prow[o] = __float2bfloat16(buf[o] * inv);
  int zlim = (qi & ~127) + 128;  // PV reads k < zlim only
  int za = (n + 7) & ~7;
  for (int o = n + tid; o < za && o < zlim; o += 256) prow[o] = __float2bfloat16(0.f);
  ushort8v zz = {0, 0, 0, 0, 0, 0, 0, 0};
  for (int o = za + tid * 8; o < zlim; o += 2048) *(ushort8v*)(prow + o) = zz;
}

extern "C" void kernel_launch(void* const* d_in, const int* in_sizes, int n_in,
                              void* d_out, int out_size, void* d_ws, size_t ws_size,
                              hipStream_t stream) {
  const float* x       = (const float*)d_in[0];
  const int*   pos     = (const int*)d_in[1];
  const float* ln1_g   = (const float*)d_in[2];
  const float* ln1_b   = (const float*)d_in[3];
  const float* mu_w    = (const float*)d_in[4];
  const float* mu_b    = (const float*)d_in[5];
  const float* proto_w = (const float*)d_in[6];
  const float* gate    = (const float*)d_in[7];
  const float* pt_w    = (const float*)d_in[8];
  const float* pln_g   = (const float*)d_in[9];
  const float* pln_b   = (const float*)d_in[10];
  const float* incoming= (const float*)d_in[11];

  // workspace layout (~302 MB); prc bf16 / f16 scores live in d_out
  char* w = (char*)d_ws;
  const long BF = 33554432L;  // bytes of one bf16 [8192][2048]
  bf16*  ln1    = (bf16*)(w);
  bf16*  qb     = (bf16*)(w + BF);
  bf16*  kb     = (bf16*)(w + 2 * BF);
  bf16*  vb     = (bf16*)(w + 3 * BF);   // unused (V written transposed)
  bf16*  attn   = (bf16*)(w + 4 * BF);
  bf16*  mu_wb  = (bf16*)(w + 5 * BF);         // [4][D][D] bf16
  bf16*  ptw_b  = (bf16*)(w + 6 * BF);         // aliased: later vT [4][D][S]
  bf16*  vT     = ptw_b;
  bf16*  inc_b  = (bf16*)(w + 7 * BF);         // aliased: later probs [4][S][S]
  bf16*  probs  = inc_b;
  float* ps3    = (float*)(w + 8 * BF);                 // [2048][2048] f32
  float* cosT   = (float*)(w + 8 * BF + 16777216L);
  float* sinT   = cosT + (long)Sh * HALF;
  float* ctx    = sinT + (long)Sh * HALF;               // [4][2048]
  float* ctxo   = ctx + Bh * Dh;
  float* routing= ctxo + Bh * Dh;                       // [16][2048]
  float* gating = routing + 16 * Dh;                    // [16][2048]
  bf16*   prc    = (bf16*)d_out;                        // bf16 [4][2048][2048]
  __half* scores = (__half*)d_out;                      // f16 [4][2048][2048]
  (void)vb;

  const long DD4 = 4L * Dh * Dh;

  hipMemsetAsync(ctx, 0, 2L * Bh * Dh * sizeof(float), stream);

  rope_table_kernel<<<(Sh * HALF) / 256, 256, 0, stream>>>(cosT, sinT);
  cvt3_kernel<<<dim3(DD4 / 1024, 3), 256, 0, stream>>>(
      mu_w, incoming, pt_w, mu_wb, inc_b, ptw_b, DD4);
  ln1_kernel<<<NROW, 256, 0, stream>>>(x, ln1_g, ln1_b, ln1);
  meanrow_kernel<<<dim3(32, 16), 256, 0, stream>>>(ln1, ctx);
  // prc[n] = incoming[n] @ pt_w[n]^T  -> prc (bf16, in d_out)
  pgemm<0><<<dim3(8, 8, 4), 512, 0, stream>>>(
      inc_b, ptw_b, prc, Dh, Dh, Dh, Dh,
      (long)Dh * Dh, (long)Dh * Dh, (long)Dh * Dh,
      nullptr, nullptr, nullptr, nullptr);
  route_kernel<<<dim3(Dh, 4), 256, 0, stream>>>(prc, proto_w, pln_g, pln_b,
                                                gate, ctx, routing, ps3);
  masnorm_kernel<<<12, 256, 0, stream>>>(routing, gating);
  // q/k/v = gating * silu(ln1 @ mu_w[n]^T + mu_b[n]); v written TRANSPOSED
  pgemm<1><<<dim3(32, 8, 3), 512, 0, stream>>>(
      ln1, mu_wb, qb, Dh, Dh, Dh, Dh,
      0L, (long)Dh * Dh, (long)NROW * Dh, mu_b, gating, nullptr, vT);
  rope_kernel<<<NROW, 256, 0, stream>>>(qb, kb, pos, cosT, sinT);
  // scores = q @ k^T * inv_sqrt_d (causal blocks only) -> f16
  pgemm<2><<<dim3(8, 8, 4), 512, 0, stream>>>(
      qb, kb, scores, Sh, Dh, Dh, Dh,
      (long)Sh * Dh, (long)Sh * Dh, (long)Sh * Sh,
      nullptr, nullptr, nullptr, nullptr);
  softmax_kernel<<<Bh * Sh, 256, 0, stream>>>((const unsigned short*)scores, probs);
  // attn = probs @ vT^T  (balanced causal kernel)
  pgemm_h<<<512, 512, 0, stream>>>(
      probs, vT, attn, Dh, Sh, Sh,
      (long)Sh * Sh, (long)Dh * Sh, (long)Sh * Dh);
  meanrow_kernel<<<dim3(32, 16), 256, 0, stream>>>(attn, ctxo);
  route_o_kernel<<<Dh, 256, 0, stream>>>(ps3, ctxo, gate, routing);
  masnorm_kernel<<<4, 256, 0, stream>>>(routing + 12 * Dh, gating + 12 * Dh);
  // out = x + gating_o * silu(attn @ mu_w[3]^T + mu_b[3])
  pgemm<4><<<dim3(32, 8, 1), 512, 0, stream>>>(
      attn, mu_wb + 3L * Dh * Dh, d_out, Dh, Dh, Dh, Dh,
      0L, 0L, 0L, mu_b + 3 * Dh, gating + 12 * Dh, x, nullptr);
}